// Round 14
// baseline (295.511 us; speedup 1.0000x reference)
//
#include <hip/hip_runtime.h>
#include <hip/hip_bf16.h>
#include <hip/hip_fp16.h>

#define B_ 2
#define S_ 1024
#define E_ 128
#define H_ 4
#define D_ 32
#define BHSD (B_ * H_ * S_ * D_)   // 262144 floats per tensor
#define LOG2E 1.44269504088896f

// ---------------------------------------------------------------------------
// Kernel A: fused QKV projection (validated R5/R8 version).
//   Q and K pre-scaled by log2(e) so attention uses bare exp2.
// ---------------------------------------------------------------------------
__global__ __launch_bounds__(128) void qkv_kernel(
    const float* __restrict__ x,
    const float* __restrict__ Wq, const float* __restrict__ bq,
    const float* __restrict__ Wk, const float* __restrict__ bk,
    const float* __restrict__ Wv, const float* __restrict__ bv,
    float* __restrict__ ws) {
  const int mat = blockIdx.y;
  const float* W    = (mat == 0) ? Wq : (mat == 1) ? Wk : Wv;
  const float* bias = (mat == 0) ? bq : (mat == 1) ? bk : bv;
  const float scale = (mat == 2) ? 1.0f : LOG2E;
  float* outbase = ws + (size_t)mat * BHSD;

  const int row0 = blockIdx.x * 8;
  const int t = threadIdx.x;

  __shared__ __align__(16) float xs[8 * E_];
  const float4* xg = (const float4*)(x + (size_t)row0 * E_);
  float4* xs4 = (float4*)xs;
  #pragma unroll
  for (int i = 0; i < 2; ++i) xs4[t + i * 128] = xg[t + i * 128];
  __syncthreads();

  const int col = t;
  const float4* W4 = (const float4*)(W + (size_t)col * E_);

  float acc[8];
  #pragma unroll
  for (int r = 0; r < 8; ++r) acc[r] = 0.f;

  #pragma unroll 4
  for (int c4 = 0; c4 < E_ / 4; ++c4) {
    float4 w = W4[c4];
    #pragma unroll
    for (int r = 0; r < 8; ++r) {
      float4 xv = xs4[r * (E_ / 4) + c4];
      acc[r] += xv.x * w.x + xv.y * w.y + xv.z * w.z + xv.w * w.w;
    }
  }

  const float bcol = bias[col];
  const int h = col >> 5, d = col & 31;
  #pragma unroll
  for (int r = 0; r < 8; ++r) {
    int row = row0 + r;
    int b = row >> 10, s = row & 1023;
    outbase[(((size_t)(b * H_ + h)) * S_ + s) * D_ + d] = (acc[r] + bcol) * scale;
  }
}

// ---------------------------------------------------------------------------
// Kernel B: ultrametric attention, DS-minimized dist[8][4] tile, register-
// pressure-fitted (peak live ~100 < 128-reg budget; R12/R13 spilled at ~135).
//   Block = 64 Q-rows x 256 keys, 256 threads = 4 waves; 128 keys/iter x 2.
//   Wave w owns keys [w*32,+32) per tile: P wave-private (no P barrier).
//   DIST loop order: per d-chunk load kv[4] once, then per row ONE qv float4
//   consumed immediately by all 4 keys (no qv[8] array -> -28 live regs).
//   DS/wave/iter: 96 DIST + 4 Pw + 64 PV + 8 stage = 172 b128 (R8: 268).
// grid = 512 blocks; LDS 63 KB -> 2 blocks/CU.
// ---------------------------------------------------------------------------
#define STR 36      // f32 LDS row stride (144 B: 16B-aligned, bank-spread)
#define PSTRH 72    // fp16 LDS row stride in halfs (144 B)

__global__ __launch_bounds__(256, 2) void attn_kernel(
    const float* __restrict__ qg, const float* __restrict__ kg_,
    const float* __restrict__ vg,
    float* __restrict__ part_o, float* __restrict__ part_l) {
  __shared__ __align__(16) float Qs[64 * STR];        //  9216 B
  __shared__ __align__(16) float Ks[128 * STR];       // 18432 B
  __shared__ __align__(16) float Vs[128 * STR];       // 18432 B
  __shared__ __align__(16) __half Ps[128 * PSTRH];    // 18432 B  (total 64512)

  const int bx = blockIdx.x;
  const int kc  = bx & 3;             // 256-key chunk 0..3
  const int rtl = (bx >> 2) & 15;     // row tile within head
  const int head = bx >> 6;           // b*H + h, 0..7
  const int t = threadIdx.x;
  const int w = t >> 6;               // wave 0..3
  const int lane = t & 63;
  const int rg = lane >> 3;           // row group: rows {rg + 8i}
  const int kg = lane & 7;            // key group (DIST) / dim group (PV)

  const float* qbase = qg  + (size_t)head * S_ * D_ + (size_t)rtl * 64 * D_;
  const float* kbase = kg_ + (size_t)head * S_ * D_ + (size_t)kc * 256 * D_;
  const float* vbase = vg  + (size_t)head * S_ * D_ + (size_t)kc * 256 * D_;

  // ---- stage Q (64x32: 2 float4/thread) + K/V keys 0..127 (4 each) ----
  {
    const float4* qsrc = (const float4*)qbase;
    #pragma unroll
    for (int i = 0; i < 2; ++i) {
      int f = t + i * 256; int r = f >> 3, c = f & 7;
      *(float4*)(Qs + r * STR + c * 4) = qsrc[f];
    }
    const float4* ksrc = (const float4*)kbase;
    const float4* vsrc = (const float4*)vbase;
    #pragma unroll
    for (int i = 0; i < 4; ++i) {
      int f = t + i * 256; int r = f >> 3, c = f & 7;
      *(float4*)(Ks + r * STR + c * 4) = ksrc[f];
      *(float4*)(Vs + r * STR + c * 4) = vsrc[f];
    }
  }

  float O[8][4];
  #pragma unroll
  for (int i = 0; i < 8; ++i)
    #pragma unroll
    for (int c = 0; c < 4; ++c) O[i][c] = 0.f;
  float lrow[8];
  #pragma unroll
  for (int i = 0; i < 8; ++i) lrow[i] = 0.f;

  __syncthreads();

  #pragma unroll
  for (int it = 0; it < 2; ++it) {
    // ---- DIST: dist[8 rows][4 keys] over 8 d-chunks ----
    float dist[8][4];
    #pragma unroll
    for (int i = 0; i < 8; ++i)
      #pragma unroll
      for (int j = 0; j < 4; ++j) dist[i][j] = 0.f;

    #pragma unroll
    for (int c = 0; c < 8; ++c) {
      const float4 kv0 = *(const float4*)(Ks + (w * 32 + kg +  0) * STR + c * 4);
      const float4 kv1 = *(const float4*)(Ks + (w * 32 + kg +  8) * STR + c * 4);
      const float4 kv2 = *(const float4*)(Ks + (w * 32 + kg + 16) * STR + c * 4);
      const float4 kv3 = *(const float4*)(Ks + (w * 32 + kg + 24) * STR + c * 4);
      #pragma unroll
      for (int i = 0; i < 8; ++i) {
        const float4 qv = *(const float4*)(Qs + (rg + 8 * i) * STR + c * 4);
        dist[i][0] = fmaxf(dist[i][0],
            fmaxf(fmaxf(fabsf(qv.x - kv0.x), fabsf(qv.y - kv0.y)),
                  fmaxf(fabsf(qv.z - kv0.z), fabsf(qv.w - kv0.w))));
        dist[i][1] = fmaxf(dist[i][1],
            fmaxf(fmaxf(fabsf(qv.x - kv1.x), fabsf(qv.y - kv1.y)),
                  fmaxf(fabsf(qv.z - kv1.z), fabsf(qv.w - kv1.w))));
        dist[i][2] = fmaxf(dist[i][2],
            fmaxf(fmaxf(fabsf(qv.x - kv2.x), fabsf(qv.y - kv2.y)),
                  fmaxf(fabsf(qv.z - kv2.z), fabsf(qv.w - kv2.w))));
        dist[i][3] = fmaxf(dist[i][3],
            fmaxf(fmaxf(fabsf(qv.x - kv3.x), fabsf(qv.y - kv3.y)),
                  fmaxf(fabsf(qv.z - kv3.z), fabsf(qv.w - kv3.w))));
      }
    }

    // ---- p = exp2(-dist); accumulate l; pack fp16; write P (wave-private) --
    #pragma unroll
    for (int j = 0; j < 4; ++j) {
      float p0 = exp2f(-dist[0][j]); lrow[0] += p0;
      float p1 = exp2f(-dist[1][j]); lrow[1] += p1;
      float p2 = exp2f(-dist[2][j]); lrow[2] += p2;
      float p3 = exp2f(-dist[3][j]); lrow[3] += p3;
      float p4 = exp2f(-dist[4][j]); lrow[4] += p4;
      float p5 = exp2f(-dist[5][j]); lrow[5] += p5;
      float p6 = exp2f(-dist[6][j]); lrow[6] += p6;
      float p7 = exp2f(-dist[7][j]); lrow[7] += p7;
      uint4 pk;
      pk.x = __builtin_bit_cast(unsigned int, __floats2half2_rn(p0, p1));
      pk.y = __builtin_bit_cast(unsigned int, __floats2half2_rn(p2, p3));
      pk.z = __builtin_bit_cast(unsigned int, __floats2half2_rn(p4, p5));
      pk.w = __builtin_bit_cast(unsigned int, __floats2half2_rn(p6, p7));
      *(uint4*)(Ps + (w * 32 + kg + 8 * j) * PSTRH + rg * 8) = pk;
    }
    // no barrier: PV reads only this wave's P keys (lgkmcnt orders RAW)

    // ---- PV: O[8r][4d] += over this wave's 32 keys ----
    #pragma unroll 4
    for (int u = 0; u < 32; ++u) {
      const int tk = w * 32 + u;
      uint4 pr = *(const uint4*)(Ps + tk * PSTRH + rg * 8);
      float4 vv = *(const float4*)(Vs + tk * STR + kg * 4);
      float2 f0 = __half22float2(__builtin_bit_cast(__half2, pr.x));
      float2 f1 = __half22float2(__builtin_bit_cast(__half2, pr.y));
      float2 f2 = __half22float2(__builtin_bit_cast(__half2, pr.z));
      float2 f3 = __half22float2(__builtin_bit_cast(__half2, pr.w));
      O[0][0] = fmaf(f0.x, vv.x, O[0][0]); O[0][1] = fmaf(f0.x, vv.y, O[0][1]);
      O[0][2] = fmaf(f0.x, vv.z, O[0][2]); O[0][3] = fmaf(f0.x, vv.w, O[0][3]);
      O[1][0] = fmaf(f0.y, vv.x, O[1][0]); O[1][1] = fmaf(f0.y, vv.y, O[1][1]);
      O[1][2] = fmaf(f0.y, vv.z, O[1][2]); O[1][3] = fmaf(f0.y, vv.w, O[1][3]);
      O[2][0] = fmaf(f1.x, vv.x, O[2][0]); O[2][1] = fmaf(f1.x, vv.y, O[2][1]);
      O[2][2] = fmaf(f1.x, vv.z, O[2][2]); O[2][3] = fmaf(f1.x, vv.w, O[2][3]);
      O[3][0] = fmaf(f1.y, vv.x, O[3][0]); O[3][1] = fmaf(f1.y, vv.y, O[3][1]);
      O[3][2] = fmaf(f1.y, vv.z, O[3][2]); O[3][3] = fmaf(f1.y, vv.w, O[3][3]);
      O[4][0] = fmaf(f2.x, vv.x, O[4][0]); O[4][1] = fmaf(f2.x, vv.y, O[4][1]);
      O[4][2] = fmaf(f2.x, vv.z, O[4][2]); O[4][3] = fmaf(f2.x, vv.w, O[4][3]);
      O[5][0] = fmaf(f2.y, vv.x, O[5][0]); O[5][1] = fmaf(f2.y, vv.y, O[5][1]);
      O[5][2] = fmaf(f2.y, vv.z, O[5][2]); O[5][3] = fmaf(f2.y, vv.w, O[5][3]);
      O[6][0] = fmaf(f3.x, vv.x, O[6][0]); O[6][1] = fmaf(f3.x, vv.y, O[6][1]);
      O[6][2] = fmaf(f3.x, vv.z, O[6][2]); O[6][3] = fmaf(f3.x, vv.w, O[6][3]);
      O[7][0] = fmaf(f3.y, vv.x, O[7][0]); O[7][1] = fmaf(f3.y, vv.y, O[7][1]);
      O[7][2] = fmaf(f3.y, vv.z, O[7][2]); O[7][3] = fmaf(f3.y, vv.w, O[7][3]);
    }

    __syncthreads();   // all waves done with Ks/Vs (and own P region)
    if (it == 0) {
      const float4* ksrc = (const float4*)(kbase + 128 * D_);
      const float4* vsrc = (const float4*)(vbase + 128 * D_);
      #pragma unroll
      for (int i = 0; i < 4; ++i) {
        int f = t + i * 256; int r = f >> 3, c = f & 7;
        *(float4*)(Ks + r * STR + c * 4) = ksrc[f];
        *(float4*)(Vs + r * STR + c * 4) = vsrc[f];
      }
      __syncthreads();
    }
  }

  // ---- reduce l across kg lanes (butterfly over lane bits 0..2) ----
  #pragma unroll
  for (int i = 0; i < 8; ++i) {
    lrow[i] += __shfl_xor(lrow[i], 1);
    lrow[i] += __shfl_xor(lrow[i], 2);
    lrow[i] += __shfl_xor(lrow[i], 4);
  }

  // ---- 4-wave O merge reusing LDS buffers; l via Ps head ----
  float* slbuf = (float*)Ps;          // 256 floats
  if (kg == 0) {
    #pragma unroll
    for (int i = 0; i < 8; ++i) slbuf[w * 64 + (rg + 8 * i)] = lrow[i];
  }
  if (w == 1) {
    #pragma unroll
    for (int i = 0; i < 8; ++i)
      *(float4*)(Ks + (rg + 8 * i) * STR + kg * 4) =
          make_float4(O[i][0], O[i][1], O[i][2], O[i][3]);
  } else if (w == 2) {
    #pragma unroll
    for (int i = 0; i < 8; ++i)
      *(float4*)(Ks + (64 + rg + 8 * i) * STR + kg * 4) =
          make_float4(O[i][0], O[i][1], O[i][2], O[i][3]);
  } else if (w == 3) {
    #pragma unroll
    for (int i = 0; i < 8; ++i)
      *(float4*)(Vs + (rg + 8 * i) * STR + kg * 4) =
          make_float4(O[i][0], O[i][1], O[i][2], O[i][3]);
  }
  __syncthreads();

  if (w == 0) {
    const size_t base = ((size_t)(head * 16 + rtl) * 4 + kc) * 64;
    #pragma unroll
    for (int i = 0; i < 8; ++i) {
      const int ar = rg + 8 * i;
      float4 a = *(const float4*)(Ks + ar * STR + kg * 4);
      float4 b = *(const float4*)(Ks + (64 + ar) * STR + kg * 4);
      float4 c = *(const float4*)(Vs + ar * STR + kg * 4);
      float4 r;
      r.x = O[i][0] + a.x + b.x + c.x;
      r.y = O[i][1] + a.y + b.y + c.y;
      r.z = O[i][2] + a.z + b.z + c.z;
      r.w = O[i][3] + a.w + b.w + c.w;
      *(float4*)(part_o + (base + ar) * 32 + kg * 4) = r;
    }
    if (kg == 0) {
      #pragma unroll
      for (int i = 0; i < 8; ++i) {
        const int ar = rg + 8 * i;
        part_l[base + ar] = slbuf[0 * 64 + ar] + slbuf[1 * 64 + ar] +
                            slbuf[2 * 64 + ar] + slbuf[3 * 64 + ar];
      }
    }
  }
}

// ---------------------------------------------------------------------------
// Kernel C: merge kc-partials -> att rows in LDS -> out = att @ Wo^T + bo
// (R3/R8/R10-validated; part layout [rt(64-row)][4 kc][64 row][32 d])
// ---------------------------------------------------------------------------
__global__ __launch_bounds__(128) void out_kernel(
    const float* __restrict__ part_o, const float* __restrict__ part_l,
    const float* __restrict__ Wo, const float* __restrict__ bo,
    float* __restrict__ out) {
  const int row0 = blockIdx.x * 8;
  const int t = threadIdx.x;

  __shared__ __align__(16) float xs[8 * E_];

  const int e = t;
  const int h = e >> 5, d = e & 31;
  #pragma unroll
  for (int i = 0; i < 8; ++i) {
    const int r = row0 + i;
    const int b = r >> 10, s = r & 1023;
    const int rt = (b * H_ + h) * 16 + (s >> 6);
    const int lrow = s & 63;
    float acc = 0.f, lsum = 0.f;
    #pragma unroll
    for (int kc = 0; kc < 4; ++kc) {
      const size_t base = (size_t)(rt * 4 + kc) * 64 + lrow;
      acc  += part_o[base * 32 + d];
      lsum += part_l[base];
    }
    xs[i * E_ + e] = acc / lsum;
  }
  __syncthreads();

  const int col = t;
  const float4* W4 = (const float4*)(Wo + (size_t)col * E_);
  const float4* xs4 = (const float4*)xs;

  float acc[8];
  #pragma unroll
  for (int r = 0; r < 8; ++r) acc[r] = 0.f;

  #pragma unroll 4
  for (int c4 = 0; c4 < E_ / 4; ++c4) {
    float4 w = W4[c4];
    #pragma unroll
    for (int r = 0; r < 8; ++r) {
      float4 xv = xs4[r * (E_ / 4) + c4];
      acc[r] += xv.x * w.x + xv.y * w.y + xv.z * w.z + xv.w * w.w;
    }
  }

  const float bcol = bo[col];
  #pragma unroll
  for (int r = 0; r < 8; ++r)
    out[(size_t)(row0 + r) * E_ + col] = acc[r] + bcol;
}

// ---------------------------------------------------------------------------
extern "C" void kernel_launch(void* const* d_in, const int* in_sizes, int n_in,
                              void* d_out, int out_size, void* d_ws, size_t ws_size,
                              hipStream_t stream) {
  const float* x  = (const float*)d_in[0];
  const float* Wq = (const float*)d_in[1];
  const float* bq = (const float*)d_in[2];
  const float* Wk = (const float*)d_in[3];
  const float* bk = (const float*)d_in[4];
  const float* Wv = (const float*)d_in[5];
  const float* bv = (const float*)d_in[6];
  const float* Wo = (const float*)d_in[7];
  const float* bo = (const float*)d_in[8];
  float* ws  = (float*)d_ws;
  float* out = (float*)d_out;

  // ws layout (floats):
  //   [0, BHSD)          q (log2e-scaled)
  //   [BHSD, 2*BHSD)     k (log2e-scaled)
  //   [2*BHSD, 3*BHSD)   v
  //   [3*BHSD, +1048576) part_o : [128 rt][4 kc][64 row][32 d]
  //   then 32768         part_l : [128 rt][4 kc][64 row]
  float* qd = ws;
  float* kd = ws + (size_t)BHSD;
  float* vd = ws + 2 * (size_t)BHSD;
  float* part_o = ws + 3 * (size_t)BHSD;
  float* part_l = part_o + (size_t)128 * 4 * 64 * 32;

  qkv_kernel<<<dim3((B_ * S_) / 8, 3), 128, 0, stream>>>(x, Wq, bq, Wk, bk, Wv, bv, ws);
  attn_kernel<<<dim3(512), 256, 0, stream>>>(qd, kd, vd, part_o, part_l);
  out_kernel<<<dim3((B_ * S_) / 8), 128, 0, stream>>>(part_o, part_l, Wo, bo, out);
}

// Round 16
// 52.271 us; speedup vs baseline: 5.6535x; 5.6535x over previous
//
#include <hip/hip_runtime.h>
#include <hip/hip_bf16.h>

#define B_ 2
#define S_ 1024
#define E_ 128
#define H_ 4
#define D_ 32
#define BHSD (B_ * H_ * S_ * D_)   // 262144 floats per tensor
#define LOG2E 1.44269504088896f

// ---------------------------------------------------------------------------
// Kernel A: fused QKV projection (validated R5/R8 version).
//   Q and K pre-scaled by log2(e) so attention uses bare exp2.
// ---------------------------------------------------------------------------
__global__ __launch_bounds__(128) void qkv_kernel(
    const float* __restrict__ x,
    const float* __restrict__ Wq, const float* __restrict__ bq,
    const float* __restrict__ Wk, const float* __restrict__ bk,
    const float* __restrict__ Wv, const float* __restrict__ bv,
    float* __restrict__ ws) {
  const int mat = blockIdx.y;
  const float* W    = (mat == 0) ? Wq : (mat == 1) ? Wk : Wv;
  const float* bias = (mat == 0) ? bq : (mat == 1) ? bk : bv;
  const float scale = (mat == 2) ? 1.0f : LOG2E;
  float* outbase = ws + (size_t)mat * BHSD;

  const int row0 = blockIdx.x * 8;
  const int t = threadIdx.x;

  __shared__ __align__(16) float xs[8 * E_];
  const float4* xg = (const float4*)(x + (size_t)row0 * E_);
  float4* xs4 = (float4*)xs;
  #pragma unroll
  for (int i = 0; i < 2; ++i) xs4[t + i * 128] = xg[t + i * 128];
  __syncthreads();

  const int col = t;
  const float4* W4 = (const float4*)(W + (size_t)col * E_);

  float acc[8];
  #pragma unroll
  for (int r = 0; r < 8; ++r) acc[r] = 0.f;

  #pragma unroll 4
  for (int c4 = 0; c4 < E_ / 4; ++c4) {
    float4 w = W4[c4];
    #pragma unroll
    for (int r = 0; r < 8; ++r) {
      float4 xv = xs4[r * (E_ / 4) + c4];
      acc[r] += xv.x * w.x + xv.y * w.y + xv.z * w.z + xv.w * w.w;
    }
  }

  const float bcol = bias[col];
  const int h = col >> 5, d = col & 31;
  #pragma unroll
  for (int r = 0; r < 8; ++r) {
    int row = row0 + r;
    int b = row >> 10, s = row & 1023;
    outbase[(((size_t)(b * H_ + h)) * S_ + s) * D_ + d] = (acc[r] + bcol) * scale;
  }
}

// ---------------------------------------------------------------------------
// Kernel B: ultrametric attention, two register-tiled "GEMMs" — R8's proven
// register shape (dist[8][2], ~84 VGPR, no scratch) with:
//   (1) V NOT staged in LDS — PV reads V via float4 global loads (L2/L1-
//       resident, independent of p -> latency hidden).
//   (2) 128 keys/block (kc=8), grid 1024; LDS 36.9 KB -> 4 blocks/CU,
//       16 waves/CU (2x R8's TLP).
//   (3) DEDICATED sm_l merge buffer (fixes R15's Ps-row/slbuf aliasing).
//   Per 64-key iteration (2 per block):
//     DIST: wave w keys [w*16,+16); lane (rg,kg) dist[8 rows rg+8i][2 keys]
//     p = exp2(-dist) -> Ps[key][storage_row] (wave-private, no barrier)
//     PV:   lane (rg,kg): O[8 rows][4 dims]; per key 2 P reads + 1 global V
//     barrier; restage K on it==0
// grid = 8 heads * 16 rowtiles * 8 kc = 1024 blocks, 256 thr (4 waves).
// ---------------------------------------------------------------------------
#define QSTRIDE 36
#define PSTRIDE 68

__global__ __launch_bounds__(256) void attn_kernel(
    const float* __restrict__ qg, const float* __restrict__ kg_,
    const float* __restrict__ vg,
    float* __restrict__ part_o, float* __restrict__ part_l) {
  __shared__ __align__(16) float Qs[64 * QSTRIDE];   //  9216 B
  __shared__ __align__(16) float Ks[64 * QSTRIDE];   //  9216 B
  __shared__ __align__(16) float Ps[64 * PSTRIDE];   // 17408 B
  __shared__ __align__(16) float sm_l[4 * 64];       //  1024 B (dedicated)

  const int bx = blockIdx.x;
  const int kc   = bx & 7;            // 128-key chunk 0..7
  const int rtl  = (bx >> 3) & 15;    // row tile within head
  const int head = bx >> 7;           // b*H + h, 0..7
  const int t = threadIdx.x;
  const int w = t >> 6;               // wave 0..3
  const int lane = t & 63;
  const int rg = lane >> 3;           // row group: rows {rg + 8i}
  const int kg = lane & 7;            // key group (DIST) / dim group (PV)

  const float* qbase = qg  + (size_t)head * S_ * D_ + (size_t)rtl * 64 * D_;
  const float* kbase = kg_ + (size_t)head * S_ * D_ + (size_t)kc * 128 * D_;
  const float* vbase = vg  + (size_t)head * S_ * D_ + (size_t)kc * 128 * D_;

  // ---- stage Q tile (64x32) + K keys 0..63: 512 float4 each, 2/thread ----
  {
    const float4* qsrc = (const float4*)qbase;
    const float4* ksrc = (const float4*)kbase;
    #pragma unroll
    for (int i = 0; i < 2; ++i) {
      int f = t + i * 256;            // 0..511
      int r = f >> 3, c4 = f & 7;
      *(float4*)(Qs + r * QSTRIDE + c4 * 4) = qsrc[f];
      *(float4*)(Ks + r * QSTRIDE + c4 * 4) = ksrc[f];
    }
  }

  float O[8][4];
  #pragma unroll
  for (int i = 0; i < 8; ++i)
    #pragma unroll
    for (int c = 0; c < 4; ++c) O[i][c] = 0.f;
  float lrow[8];
  #pragma unroll
  for (int i = 0; i < 8; ++i) lrow[i] = 0.f;

  __syncthreads();

  #pragma unroll
  for (int it = 0; it < 2; ++it) {
    // ---- DIST: dist[8 rows][2 keys] over 8 d-chunks ----
    float dist[8][2];
    #pragma unroll
    for (int i = 0; i < 8; ++i) { dist[i][0] = 0.f; dist[i][1] = 0.f; }

    #pragma unroll 2
    for (int c = 0; c < 8; ++c) {
      float4 qv[8];
      #pragma unroll
      for (int i = 0; i < 8; ++i)
        qv[i] = *(const float4*)(Qs + (rg + 8 * i) * QSTRIDE + c * 4);
      float4 kv[2];
      #pragma unroll
      for (int j = 0; j < 2; ++j)
        kv[j] = *(const float4*)(Ks + (w * 16 + kg + 8 * j) * QSTRIDE + c * 4);
      #pragma unroll
      for (int i = 0; i < 8; ++i) {
        #pragma unroll
        for (int j = 0; j < 2; ++j) {
          float m0 = fmaxf(fabsf(qv[i].x - kv[j].x), fabsf(qv[i].y - kv[j].y));
          float m1 = fmaxf(fabsf(qv[i].z - kv[j].z), fabsf(qv[i].w - kv[j].w));
          dist[i][j] = fmaxf(dist[i][j], fmaxf(m0, m1));
        }
      }
    }

    // ---- p = exp2(-dist); accumulate l; write P transposed (wave-private) --
    float pp[8][2];
    #pragma unroll
    for (int i = 0; i < 8; ++i) {
      #pragma unroll
      for (int j = 0; j < 2; ++j) {
        float p = exp2f(-dist[i][j]);     // dist pre-scaled by log2e
        pp[i][j] = p;
        lrow[i] += p;
      }
    }
    #pragma unroll
    for (int j = 0; j < 2; ++j) {
      float* dst = Ps + (w * 16 + kg + 8 * j) * PSTRIDE + rg * 8;
      *(float4*)(dst + 0) = make_float4(pp[0][j], pp[1][j], pp[2][j], pp[3][j]);
      *(float4*)(dst + 4) = make_float4(pp[4][j], pp[5][j], pp[6][j], pp[7][j]);
    }
    // no barrier: PV reads only this wave's P rows (lgkmcnt orders RAW)

    // ---- PV: O[8r][4d] += over this wave's 16 keys; V from global ----
    const float* vG = vbase + (size_t)(it * 64) * D_ + kg * 4;
    const int tk0 = w * 16;
    #pragma unroll 4
    for (int u = 0; u < 16; ++u) {
      const int tk = tk0 + u;
      float4 pa = *(const float4*)(Ps + tk * PSTRIDE + rg * 8);
      float4 pb = *(const float4*)(Ps + tk * PSTRIDE + rg * 8 + 4);
      float4 vv = *(const float4*)(vG + (size_t)tk * D_);
      O[0][0] = fmaf(pa.x, vv.x, O[0][0]); O[0][1] = fmaf(pa.x, vv.y, O[0][1]);
      O[0][2] = fmaf(pa.x, vv.z, O[0][2]); O[0][3] = fmaf(pa.x, vv.w, O[0][3]);
      O[1][0] = fmaf(pa.y, vv.x, O[1][0]); O[1][1] = fmaf(pa.y, vv.y, O[1][1]);
      O[1][2] = fmaf(pa.y, vv.z, O[1][2]); O[1][3] = fmaf(pa.y, vv.w, O[1][3]);
      O[2][0] = fmaf(pa.z, vv.x, O[2][0]); O[2][1] = fmaf(pa.z, vv.y, O[2][1]);
      O[2][2] = fmaf(pa.z, vv.z, O[2][2]); O[2][3] = fmaf(pa.z, vv.w, O[2][3]);
      O[3][0] = fmaf(pa.w, vv.x, O[3][0]); O[3][1] = fmaf(pa.w, vv.y, O[3][1]);
      O[3][2] = fmaf(pa.w, vv.z, O[3][2]); O[3][3] = fmaf(pa.w, vv.w, O[3][3]);
      O[4][0] = fmaf(pb.x, vv.x, O[4][0]); O[4][1] = fmaf(pb.x, vv.y, O[4][1]);
      O[4][2] = fmaf(pb.x, vv.z, O[4][2]); O[4][3] = fmaf(pb.x, vv.w, O[4][3]);
      O[5][0] = fmaf(pb.y, vv.x, O[5][0]); O[5][1] = fmaf(pb.y, vv.y, O[5][1]);
      O[5][2] = fmaf(pb.y, vv.z, O[5][2]); O[5][3] = fmaf(pb.y, vv.w, O[5][3]);
      O[6][0] = fmaf(pb.z, vv.x, O[6][0]); O[6][1] = fmaf(pb.z, vv.y, O[6][1]);
      O[6][2] = fmaf(pb.z, vv.z, O[6][2]); O[6][3] = fmaf(pb.z, vv.w, O[6][3]);
      O[7][0] = fmaf(pb.w, vv.x, O[7][0]); O[7][1] = fmaf(pb.w, vv.y, O[7][1]);
      O[7][2] = fmaf(pb.w, vv.z, O[7][2]); O[7][3] = fmaf(pb.w, vv.w, O[7][3]);
    }

    __syncthreads();   // all waves done reading Ks/Ps -> safe to restage K
    if (it == 0) {
      const float4* ksrc = (const float4*)(kbase + 64 * D_);
      #pragma unroll
      for (int i = 0; i < 2; ++i) {
        int f = t + i * 256;
        int r = f >> 3, c4 = f & 7;
        *(float4*)(Ks + r * QSTRIDE + c4 * 4) = ksrc[f];
      }
      __syncthreads();
    }
  }

  // ---- reduce l across kg lanes (butterfly over lane bits 0..2) ----
  #pragma unroll
  for (int i = 0; i < 8; ++i) {
    lrow[i] += __shfl_xor(lrow[i], 1);
    lrow[i] += __shfl_xor(lrow[i], 2);
    lrow[i] += __shfl_xor(lrow[i], 4);
  }

  // ---- 4-wave O merge: Ks/Qs/Ps rows; l via DEDICATED sm_l ----
  if (kg == 0) {
    #pragma unroll
    for (int i = 0; i < 8; ++i) sm_l[w * 64 + (rg + 8 * i)] = lrow[i];
  }
  if (w == 1) {
    #pragma unroll
    for (int i = 0; i < 8; ++i)
      *(float4*)(Ks + (rg + 8 * i) * QSTRIDE + kg * 4) =
          make_float4(O[i][0], O[i][1], O[i][2], O[i][3]);
  } else if (w == 2) {
    #pragma unroll
    for (int i = 0; i < 8; ++i)
      *(float4*)(Qs + (rg + 8 * i) * QSTRIDE + kg * 4) =
          make_float4(O[i][0], O[i][1], O[i][2], O[i][3]);
  } else if (w == 3) {
    #pragma unroll
    for (int i = 0; i < 8; ++i)
      *(float4*)(Ps + (rg + 8 * i) * PSTRIDE + kg * 4) =
          make_float4(O[i][0], O[i][1], O[i][2], O[i][3]);
  }
  __syncthreads();

  if (w == 0) {
    const size_t base = ((size_t)((head * 16 + rtl) * 8 + kc)) * 64;
    #pragma unroll
    for (int i = 0; i < 8; ++i) {
      const int ar = rg + 8 * i;
      float4 a = *(const float4*)(Ks + ar * QSTRIDE + kg * 4);
      float4 b = *(const float4*)(Qs + ar * QSTRIDE + kg * 4);
      float4 c = *(const float4*)(Ps + ar * PSTRIDE + kg * 4);
      float4 r;
      r.x = O[i][0] + a.x + b.x + c.x;
      r.y = O[i][1] + a.y + b.y + c.y;
      r.z = O[i][2] + a.z + b.z + c.z;
      r.w = O[i][3] + a.w + b.w + c.w;
      *(float4*)(part_o + (base + ar) * 32 + kg * 4) = r;
    }
    if (kg == 0) {
      #pragma unroll
      for (int i = 0; i < 8; ++i) {
        const int ar = rg + 8 * i;
        part_l[base + ar] = sm_l[0 * 64 + ar] + sm_l[1 * 64 + ar] +
                            sm_l[2 * 64 + ar] + sm_l[3 * 64 + ar];
      }
    }
  }
}

// ---------------------------------------------------------------------------
// Kernel C: merge 8 kc-partials -> att rows in LDS -> out = att @ Wo^T + bo
// part layout: [rt = (b*H+h)*16 + s/64][8 kc][64 row][32 d]
// ---------------------------------------------------------------------------
__global__ __launch_bounds__(128) void out_kernel(
    const float* __restrict__ part_o, const float* __restrict__ part_l,
    const float* __restrict__ Wo, const float* __restrict__ bo,
    float* __restrict__ out) {
  const int row0 = blockIdx.x * 8;
  const int t = threadIdx.x;

  __shared__ __align__(16) float xs[8 * E_];

  const int e = t;
  const int h = e >> 5, d = e & 31;
  #pragma unroll
  for (int i = 0; i < 8; ++i) {
    const int r = row0 + i;
    const int b = r >> 10, s = r & 1023;
    const int rt = (b * H_ + h) * 16 + (s >> 6);
    const int lrow = s & 63;
    float acc = 0.f, lsum = 0.f;
    #pragma unroll
    for (int kc = 0; kc < 8; ++kc) {
      const size_t base = ((size_t)(rt * 8 + kc)) * 64 + lrow;
      acc  += part_o[base * 32 + d];
      lsum += part_l[base];
    }
    xs[i * E_ + e] = acc / lsum;
  }
  __syncthreads();

  const int col = t;
  const float4* W4 = (const float4*)(Wo + (size_t)col * E_);
  const float4* xs4 = (const float4*)xs;

  float acc[8];
  #pragma unroll
  for (int r = 0; r < 8; ++r) acc[r] = 0.f;

  #pragma unroll 4
  for (int c4 = 0; c4 < E_ / 4; ++c4) {
    float4 w = W4[c4];
    #pragma unroll
    for (int r = 0; r < 8; ++r) {
      float4 xv = xs4[r * (E_ / 4) + c4];
      acc[r] += xv.x * w.x + xv.y * w.y + xv.z * w.z + xv.w * w.w;
    }
  }

  const float bcol = bo[col];
  #pragma unroll
  for (int r = 0; r < 8; ++r)
    out[(size_t)(row0 + r) * E_ + col] = acc[r] + bcol;
}

// ---------------------------------------------------------------------------
extern "C" void kernel_launch(void* const* d_in, const int* in_sizes, int n_in,
                              void* d_out, int out_size, void* d_ws, size_t ws_size,
                              hipStream_t stream) {
  const float* x  = (const float*)d_in[0];
  const float* Wq = (const float*)d_in[1];
  const float* bq = (const float*)d_in[2];
  const float* Wk = (const float*)d_in[3];
  const float* bk = (const float*)d_in[4];
  const float* Wv = (const float*)d_in[5];
  const float* bv = (const float*)d_in[6];
  const float* Wo = (const float*)d_in[7];
  const float* bo = (const float*)d_in[8];
  float* ws  = (float*)d_ws;
  float* out = (float*)d_out;

  // ws layout (floats):
  //   [0, BHSD)          q (log2e-scaled)
  //   [BHSD, 2*BHSD)     k (log2e-scaled)
  //   [2*BHSD, 3*BHSD)   v
  //   [3*BHSD, +2097152) part_o : [128 rt][8 kc][64 row][32 d]
  //   then 65536         part_l : [128 rt][8 kc][64 row]
  float* qd = ws;
  float* kd = ws + (size_t)BHSD;
  float* vd = ws + 2 * (size_t)BHSD;
  float* part_o = ws + 3 * (size_t)BHSD;
  float* part_l = part_o + (size_t)128 * 8 * 64 * 32;

  qkv_kernel<<<dim3((B_ * S_) / 8, 3), 128, 0, stream>>>(x, Wq, bq, Wk, bk, Wv, bv, ws);
  attn_kernel<<<dim3(1024), 256, 0, stream>>>(qd, kd, vd, part_o, part_l);
  out_kernel<<<dim3((B_ * S_) / 8), 128, 0, stream>>>(part_o, part_l, Wo, bo, out);
}